// Round 15
// baseline (1496.669 us; speedup 1.0000x reference)
//
#include <hip/hip_runtime.h>
#include <hip/hip_bf16.h>
#include <stdint.h>

typedef __bf16 bf16x8 __attribute__((ext_vector_type(8)));
typedef float  f32x4  __attribute__((ext_vector_type(4)));

#define BAR()  asm volatile("s_waitcnt lgkmcnt(0)\n\ts_barrier" ::: "memory")
#define SB()   __builtin_amdgcn_sched_barrier(0)

static __device__ __forceinline__ float sigm(float x) {
  return __builtin_amdgcn_rcpf(1.0f + __builtin_amdgcn_exp2f(x * -1.4426950408889634f));
}
static __device__ __forceinline__ float tanh_fast(float x) {
  return 1.0f - 2.0f * __builtin_amdgcn_rcpf(1.0f + __builtin_amdgcn_exp2f(x * 2.8853900817779268f));
}
static __device__ __forceinline__ unsigned short f2bf(float f) {
  return __builtin_bit_cast(unsigned short, (__bf16)f);
}
static __device__ __forceinline__ float bf2f(unsigned short u) {
  union { uint32_t i; float f; } v; v.i = ((uint32_t)u) << 16; return v.f;
}
static __device__ __forceinline__ void async16(const float* g, float* l) {
  __builtin_amdgcn_global_load_lds((__attribute__((address_space(1))) void*)g,
                                   (__attribute__((address_space(3))) void*)l, 16, 0, 0);
}
static __device__ __forceinline__ uint32_t aload_acq(uint32_t* p) {
  return __hip_atomic_load(p, __ATOMIC_ACQUIRE, __HIP_MEMORY_SCOPE_AGENT);
}
static __device__ __forceinline__ void astore_rel(uint32_t* p, uint32_t v) {
  __hip_atomic_store(p, v, __ATOMIC_RELEASE, __HIP_MEMORY_SCOPE_AGENT);
}

// Cross-WG layer pipeline: 128 WGs x 512 threads.
//   blocks 0..63  (A): layer 0 for batch rows p*16..+15. Weights W0(folded)+Whh0
//                      fully register-resident (96 regs). Publishes h0(t) (4KB,
//                      frag-linear) into a D-slot ring in d_ws.
//   blocks 64..127(B): layer 1 + head for the same rows. Wih1+Whh1 fully
//                      register-resident (128 regs) -> ZERO weight LDS reads.
// Sync: device-scope release/acquire flags (prod/cons), one 64B line per pair.
// Consumer polls amortized (~1 acquire per D steps, tid0-only + __syncthreads
// handoff); producer paced by cons flag (ring backpressure). Flags zeroed each
// launch via hipMemsetAsync (graph-capturable). Deadlock-free: 128 WGs all
// co-resident (1 WG/CU at 40KB LDS, 8 waves), classic bounded-buffer protocol.
__global__ __launch_bounds__(512) __attribute__((amdgpu_waves_per_eu(2, 2)))
void fraud_lstm_split(
    const float* __restrict__ x,     const float* __restrict__ Wproj,
    const float* __restrict__ bproj, const float* __restrict__ Wih0,
    const float* __restrict__ Whh0,  const float* __restrict__ bih0,
    const float* __restrict__ bhh0,  const float* __restrict__ Wih1,
    const float* __restrict__ Whh1,  const float* __restrict__ bih1,
    const float* __restrict__ bhh1,  const float* __restrict__ Wh1,
    const float* __restrict__ bh1,   const float* __restrict__ Wh2,
    const float* __restrict__ bh2,   float* __restrict__ out,
    uint32_t* __restrict__ wsp, int D)
{
  __shared__ float sStage[4096];            // 16KB: A Wproj-fold stage; B head scratch
  __shared__ unsigned short sH0f[2][2048];  // A: h0 dbuf, frag-linear [kk][lane][8]
  __shared__ unsigned short sH1f[2][2048];  // B: h1 dbuf
  __shared__ float sXB[2][1024];            // A: x dbuf, frag-linear
  __shared__ uint32_t sFlag;                // poll broadcast

  const int tid  = threadIdx.x;
  const int lane = tid & 63;
  const int wid  = tid >> 6;
  const int lr   = lane & 15;
  const int lg   = lane >> 4;
  const int g0   = wid*16 + lr;
  const int hwb  = (g0 >> 5)*1024 + ((g0 >> 3) & 3)*256 + (g0 & 7)*2 + lg*64;
  const int lb   = lane * 16;
  const int Dm   = D - 1;                   // D is a power of two

  if (blockIdx.x < 64) {
    // ================= A: layer-0 producer =================
    const int p  = blockIdx.x;
    const int b0 = p * 16;
    uint32_t* prodf = wsp + p*16;           // 64B-spaced flags
    uint32_t* consf = wsp + 1024 + p*16;
    char* slots = (char*)wsp + 8192 + (size_t)p * D * 4096;

    // stage Wproj (f32 [p=64][f=64])
    for (int i = tid; i < 4096; i += 512) sStage[i] = Wproj[i];
    __syncthreads();

    // fold W0 = Wih0 @ Wproj (per-lane f32); fold biases
    float w0a[2][4][8];
    #pragma unroll
    for (int kk = 0; kk < 2; ++kk)
      #pragma unroll
      for (int n = 0; n < 4; ++n)
        #pragma unroll
        for (int j = 0; j < 8; ++j) w0a[kk][n][j] = 0.f;
    float bacc[4] = {0.f, 0.f, 0.f, 0.f};
    #pragma unroll 2
    for (int pp = 0; pp < 64; ++pp) {
      float av[4];
      #pragma unroll
      for (int n = 0; n < 4; ++n) av[n] = Wih0[(n*128 + g0)*64 + pp];
      float bp = bproj[pp];
      #pragma unroll
      for (int n = 0; n < 4; ++n) bacc[n] += av[n] * bp;
      #pragma unroll
      for (int kk = 0; kk < 2; ++kk) {
        f32x4 wa = *(const f32x4*)&sStage[pp*64 + kk*32 + lg*8];
        f32x4 wb = *(const f32x4*)&sStage[pp*64 + kk*32 + lg*8 + 4];
        #pragma unroll
        for (int n = 0; n < 4; ++n)
          #pragma unroll
          for (int j = 0; j < 4; ++j) {
            w0a[kk][n][j]     += av[n] * wa[j];
            w0a[kk][n][4 + j] += av[n] * wb[j];
          }
      }
    }
    bf16x8 w0f[2][4];
    #pragma unroll
    for (int kk = 0; kk < 2; ++kk)
      #pragma unroll
      for (int n = 0; n < 4; ++n)
        #pragma unroll
        for (int j = 0; j < 8; ++j) w0f[kk][n][j] = (__bf16)w0a[kk][n][j];
    float b0r[4];
    #pragma unroll
    for (int n = 0; n < 4; ++n) {
      const int g = n*128 + g0;
      b0r[n] = bih0[g] + bhh0[g] + bacc[n];
    }

    // whh0 -> regs
    bf16x8 whh0[4][4];
    #pragma unroll
    for (int n = 0; n < 4; ++n)
      #pragma unroll
      for (int kk = 0; kk < 4; ++kk) {
        const float* p0 = Whh0 + (n*128 + g0)*128 + kk*32 + lg*8;
        #pragma unroll
        for (int j = 0; j < 8; ++j) whh0[n][kk][j] = (__bf16)p0[j];
      }

    for (int i = tid; i < 2048; i += 512) { sH0f[0][i] = 0; sH0f[1][i] = 0; }

    // x staging: frag-linear, per-lane permuted global source (proven R10 path)
    const float* xw = x + (size_t)(b0 + (lane & 15)) * (512*64)
                        + ((wid >> 1) & 1) * 32 + (lane >> 4) * 8 + (wid & 1) * 4;
    if (wid < 4) async16(xw, &sXB[0][wid*256]);   // x(0)
    __syncthreads();   // vmcnt+lgkm drained: x(0) landed, h0 zeroed, fold visible

    f32x4 c0r = {0.f,0.f,0.f,0.f};
    uint32_t kc = 0;   // last-seen cons flag (uniform across block)

    #pragma unroll 1
    for (int t = 0; t < 512; ++t) {
      const int cur = t & 1;
      if (wid < 4 && t < 511) async16(xw + (t + 1)*64, &sXB[cur ^ 1][wid*256]);

      const char* xp  = (const char*)sXB[cur] + lb;
      const char* h0p = (const char*)sH0f[cur ^ 1] + lb;
      char* hw0 = (char*)sH0f[cur] + hwb;

      f32x4 acc0[4];
      #pragma unroll
      for (int n = 0; n < 4; ++n) acc0[n] = f32x4{b0r[n], b0r[n], b0r[n], b0r[n]};
      #pragma unroll
      for (int kk = 0; kk < 2; ++kk) {
        f32x4 a0 = *(const f32x4*)(xp + kk*2048);
        f32x4 a1 = *(const f32x4*)(xp + kk*2048 + 1024);
        bf16x8 xa;
        #pragma unroll
        for (int j = 0; j < 4; ++j) { xa[j] = (__bf16)a0[j]; xa[4+j] = (__bf16)a1[j]; }
        #pragma unroll
        for (int n = 0; n < 4; ++n)
          acc0[n] = __builtin_amdgcn_mfma_f32_16x16x32_bf16(xa, w0f[kk][n], acc0[n], 0, 0, 0);
        SB();
      }
      #pragma unroll
      for (int kk = 0; kk < 4; ++kk) {
        bf16x8 ha = *(const bf16x8*)(h0p + kk*1024);
        #pragma unroll
        for (int n = 0; n < 4; ++n)
          acc0[n] = __builtin_amdgcn_mfma_f32_16x16x32_bf16(ha, whh0[n][kk], acc0[n], 0, 0, 0);
        SB();
      }
      #pragma unroll
      for (int r = 0; r < 4; ++r) {
        float iv = sigm(acc0[0][r]);
        float fv = sigm(acc0[1][r]);
        float gv = tanh_fast(acc0[2][r]);
        float ov = sigm(acc0[3][r]);
        float c  = fv * c0r[r] + iv * gv;
        c0r[r] = c;
        *(unsigned short*)(hw0 + r*16) = f2bf(ov * tanh_fast(c));
      }
      SB();

      // ring backpressure: slot t%D free iff cons >= t+1-D (uniform branch)
      if (t >= D && (int)kc < t + 1 - D) {
        if (tid == 0) {
          uint32_t v = aload_acq(consf);
          while ((int)v < t + 1 - D) { __builtin_amdgcn_s_sleep(2); v = aload_acq(consf); }
          sFlag = v;
        }
        __syncthreads();
        kc = sFlag;
      }
      __syncthreads();   // h0(t) LDS visible for copy (drains vmcnt/lgkm)
      // publish: 4KB LDS -> slot, 512 threads x 8B, coalesced
      *(uint64_t*)(slots + (size_t)(t & Dm)*4096 + tid*8) =
          *(const uint64_t*)((const char*)sH0f[cur] + tid*8);
      __syncthreads();   // all slot stores performed
      if (tid == 0) astore_rel(prodf, (uint32_t)(t + 1));
    }
    return;
  }

  // ================= B: layer-1 consumer + head =================
  {
    const int p  = blockIdx.x - 64;
    const int b0 = p * 16;
    uint32_t* prodf = wsp + p*16;
    uint32_t* consf = wsp + 1024 + p*16;
    const char* slots = (const char*)wsp + 8192 + (size_t)p * D * 4096;

    // wih1, whh1 -> regs (128 total)
    bf16x8 wih1[4][4], whh1[4][4];
    #pragma unroll
    for (int n = 0; n < 4; ++n)
      #pragma unroll
      for (int kk = 0; kk < 4; ++kk) {
        const int ro = (n*128 + g0)*128 + kk*32 + lg*8;
        const float* p1 = Wih1 + ro;
        const float* p2 = Whh1 + ro;
        #pragma unroll
        for (int j = 0; j < 8; ++j) {
          wih1[n][kk][j] = (__bf16)p1[j];
          whh1[n][kk][j] = (__bf16)p2[j];
        }
      }
    float b1r[4];
    #pragma unroll
    for (int n = 0; n < 4; ++n) {
      const int g = n*128 + g0;
      b1r[n] = bih1[g] + bhh1[g];
    }
    for (int i = tid; i < 2048; i += 512) { sH1f[0][i] = 0; sH1f[1][i] = 0; }
    __syncthreads();

    f32x4 c1r = {0.f,0.f,0.f,0.f};
    uint32_t kp = 0;   // last-seen prod flag (uniform)

    #pragma unroll 1
    for (int t = 0; t < 512; ++t) {
      const int cur = t & 1;

      // wait for h0(t): amortized poll (~1 acquire per D steps)
      if (kp < (uint32_t)(t + 1)) {
        if (tid == 0) {
          uint32_t v = aload_acq(prodf);
          while (v < (uint32_t)(t + 1)) { __builtin_amdgcn_s_sleep(2); v = aload_acq(prodf); }
          sFlag = v;
        }
        __syncthreads();
        kp = sFlag;
      }

      // issue h0(t) fragment loads (coalesced 1KB per kk per wave)
      const char* sl = slots + (size_t)(t & Dm)*4096 + lb;
      bf16x8 h0a0 = *(const bf16x8*)(sl);
      bf16x8 h0a1 = *(const bf16x8*)(sl + 1024);
      bf16x8 h0a2 = *(const bf16x8*)(sl + 2048);
      bf16x8 h0a3 = *(const bf16x8*)(sl + 3072);
      SB();

      f32x4 acc1[4];
      #pragma unroll
      for (int n = 0; n < 4; ++n) acc1[n] = f32x4{b1r[n], b1r[n], b1r[n], b1r[n]};

      // h1(t-1) @ Whh1^T  (h1 from LDS, weights in regs) — hides h0 load latency
      const char* h1p = (const char*)sH1f[cur ^ 1] + lb;
      #pragma unroll
      for (int kk = 0; kk < 4; ++kk) {
        bf16x8 ha = *(const bf16x8*)(h1p + kk*1024);
        #pragma unroll
        for (int n = 0; n < 4; ++n)
          acc1[n] = __builtin_amdgcn_mfma_f32_16x16x32_bf16(ha, whh1[n][kk], acc1[n], 0, 0, 0);
        SB();
      }
      // h0(t) @ Wih1^T  (pure register)
      #pragma unroll
      for (int n = 0; n < 4; ++n)
        acc1[n] = __builtin_amdgcn_mfma_f32_16x16x32_bf16(h0a0, wih1[n][0], acc1[n], 0, 0, 0);
      SB();
      #pragma unroll
      for (int n = 0; n < 4; ++n)
        acc1[n] = __builtin_amdgcn_mfma_f32_16x16x32_bf16(h0a1, wih1[n][1], acc1[n], 0, 0, 0);
      SB();
      #pragma unroll
      for (int n = 0; n < 4; ++n)
        acc1[n] = __builtin_amdgcn_mfma_f32_16x16x32_bf16(h0a2, wih1[n][2], acc1[n], 0, 0, 0);
      SB();
      #pragma unroll
      for (int n = 0; n < 4; ++n)
        acc1[n] = __builtin_amdgcn_mfma_f32_16x16x32_bf16(h0a3, wih1[n][3], acc1[n], 0, 0, 0);
      SB();

      // pointwise 1 -> h1(t)
      char* hw = (char*)sH1f[cur] + hwb;
      #pragma unroll
      for (int r = 0; r < 4; ++r) {
        float iv = sigm(acc1[0][r]);
        float fv = sigm(acc1[1][r]);
        float gv = tanh_fast(acc1[2][r]);
        float ov = sigm(acc1[3][r]);
        float c  = fv * c1r[r] + iv * gv;
        c1r[r] = c;
        *(unsigned short*)(hw + r*16) = f2bf(ov * tanh_fast(c));
      }

      __syncthreads();   // h0 loads performed (vmcnt drained) + h1(t) visible
      if (tid == 0) astore_rel(consf, (uint32_t)(t + 1));
    }

    // head: hid = relu(h1@Wh1^T + bh1); out = hid@Wh2^T + bh2.  h1(511) in sH1f[1].
    {
      int row = tid >> 5;
      int j0  = (tid & 31) * 2;
      float a0 = bh1[j0], a1 = bh1[j0 + 1];
      const float* w0 = Wh1 + j0*128;
      const float* w1 = w0 + 128;
      #pragma unroll 8
      for (int k = 0; k < 128; ++k) {
        float hv = bf2f(sH1f[1][(k >> 5)*512 + ((k >> 3) & 3)*128 + row*8 + (k & 7)]);
        a0 += hv * w0[k];
        a1 += hv * w1[k];
      }
      sStage[row*64 + j0]     = fmaxf(a0, 0.f);
      sStage[row*64 + j0 + 1] = fmaxf(a1, 0.f);
    }
    BAR();
    if (tid < 16) {
      float a = bh2[0];
      #pragma unroll 8
      for (int j = 0; j < 64; ++j) a += sStage[tid*64 + j] * Wh2[j];
      out[b0 + tid] = a;
    }
  }
}

extern "C" void kernel_launch(void* const* d_in, const int* in_sizes, int n_in,
                              void* d_out, int out_size, void* d_ws, size_t ws_size,
                              hipStream_t stream) {
  (void)in_sizes; (void)n_in; (void)out_size;
  const float* x     = (const float*)d_in[0];
  const float* Wproj = (const float*)d_in[2];
  const float* bproj = (const float*)d_in[3];
  const float* Wih0  = (const float*)d_in[4];
  const float* Whh0  = (const float*)d_in[5];
  const float* bih0  = (const float*)d_in[6];
  const float* bhh0  = (const float*)d_in[7];
  const float* Wih1  = (const float*)d_in[8];
  const float* Whh1  = (const float*)d_in[9];
  const float* bih1  = (const float*)d_in[10];
  const float* bhh1  = (const float*)d_in[11];
  const float* Wh1   = (const float*)d_in[12];
  const float* bh1   = (const float*)d_in[13];
  const float* Wh2   = (const float*)d_in[14];
  const float* bh2   = (const float*)d_in[15];
  float* out = (float*)d_out;
  uint32_t* wsp = (uint32_t*)d_ws;

  // ring depth from workspace size (power of two)
  int D = (ws_size >= 8192 + (size_t)64*8*4096) ? 8
        : (ws_size >= 8192 + (size_t)64*4*4096) ? 4
        : (ws_size >= 8192 + (size_t)64*2*4096) ? 2 : 1;

  // zero prod/cons flags every call (graph-capturable, deterministic replay)
  hipMemsetAsync(d_ws, 0, 8192, stream);

  hipLaunchKernelGGL(fraud_lstm_split, dim3(128), dim3(512), 0, stream,
                     x, Wproj, bproj, Wih0, Whh0, bih0, bhh0,
                     Wih1, Whh1, bih1, bhh1, Wh1, bh1, Wh2, bh2, out, wsp, D);
}

// Round 16
// 1116.651 us; speedup vs baseline: 1.3403x; 1.3403x over previous
//
#include <hip/hip_runtime.h>
#include <hip/hip_bf16.h>
#include <stdint.h>

typedef __bf16 bf16x8 __attribute__((ext_vector_type(8)));
typedef float  f32x4  __attribute__((ext_vector_type(4)));

#define BAR()  asm volatile("s_waitcnt lgkmcnt(0)\n\ts_barrier" ::: "memory")
#define SB()   __builtin_amdgcn_sched_barrier(0)

static __device__ __forceinline__ float sigm(float x) {
  return __builtin_amdgcn_rcpf(1.0f + __builtin_amdgcn_exp2f(x * -1.4426950408889634f));
}
static __device__ __forceinline__ float tanh_fast(float x) {
  return 1.0f - 2.0f * __builtin_amdgcn_rcpf(1.0f + __builtin_amdgcn_exp2f(x * 2.8853900817779268f));
}
static __device__ __forceinline__ unsigned short f2bf(float f) {
  return __builtin_bit_cast(unsigned short, (__bf16)f);
}
static __device__ __forceinline__ float bf2f(unsigned short u) {
  union { uint32_t i; float f; } v; v.i = ((uint32_t)u) << 16; return v.f;
}
static __device__ __forceinline__ void async16(const float* g, float* l) {
  __builtin_amdgcn_global_load_lds((__attribute__((address_space(1))) void*)g,
                                   (__attribute__((address_space(3))) void*)l, 16, 0, 0);
}

// BEST KNOWN (R10/R14, 1116-1117 us) — final restore after the cross-WG layer
// pipeline (R15: 1496 us, global handoff round trip on the critical path) and
// six intra-wave scheduling variants (R6/R8/R9/R11/R12/R13) all regressed.
// 64 WGs x 512 threads persistent; wave wid owns h-cols wid*16..+15 (gate types
// i,f,g,o as its 4 MFMA N-tiles). One barrier/step: region t = A(t) + B(t-1),
// data-independent within the region (B consumes only last-region buffers).
// PHASE SKEW: waves 0-3 execute A;B, waves 4-7 execute B;A.
// Weights: whh0 + wih1 + folded W0 in registers (160); Whh1 in LDS
// fragment-linear (ds_read_b128 at lane*16, conflict-free by construction).
// Register discipline: adjacent-read SB-fenced clusters only (~250-reg cliff).
#define SEC_A() do {                                                           \
    f32x4 acc0[4];                                                             \
    _Pragma("unroll")                                                          \
    for (int n = 0; n < 4; ++n) acc0[n] = f32x4{b0r[n],b0r[n],b0r[n],b0r[n]};  \
    _Pragma("unroll")                                                          \
    for (int kk = 0; kk < 2; ++kk) {                                           \
      f32x4 a0 = *(const f32x4*)(xp + kk*2048);                                \
      f32x4 a1 = *(const f32x4*)(xp + kk*2048 + 1024);                         \
      bf16x8 xa;                                                               \
      _Pragma("unroll")                                                        \
      for (int j = 0; j < 4; ++j) { xa[j] = (__bf16)a0[j]; xa[4+j] = (__bf16)a1[j]; } \
      _Pragma("unroll")                                                        \
      for (int n = 0; n < 4; ++n)                                              \
        acc0[n] = __builtin_amdgcn_mfma_f32_16x16x32_bf16(xa, w0f[kk][n], acc0[n], 0, 0, 0); \
      SB();                                                                    \
    }                                                                          \
    _Pragma("unroll")                                                          \
    for (int kk = 0; kk < 4; ++kk) {                                           \
      bf16x8 ha = *(const bf16x8*)(h0p + kk*1024);                             \
      _Pragma("unroll")                                                        \
      for (int n = 0; n < 4; ++n)                                              \
        acc0[n] = __builtin_amdgcn_mfma_f32_16x16x32_bf16(ha, whh0[n][kk], acc0[n], 0, 0, 0); \
      SB();                                                                    \
    }                                                                          \
    _Pragma("unroll")                                                          \
    for (int r = 0; r < 4; ++r) {                                              \
      float iv = sigm(acc0[0][r]);                                             \
      float fv = sigm(acc0[1][r]);                                             \
      float gv = tanh_fast(acc0[2][r]);                                        \
      float ov = sigm(acc0[3][r]);                                             \
      float c  = fv * c0r[r] + iv * gv;                                        \
      c0r[r] = c;                                                              \
      *(unsigned short*)(hw0 + r*16) = f2bf(ov * tanh_fast(c));                \
    }                                                                          \
    SB();                                                                      \
  } while (0)

#define SEC_B() do {                                                           \
    f32x4 acc1[4];                                                             \
    _Pragma("unroll")                                                          \
    for (int n = 0; n < 4; ++n) acc1[n] = f32x4{b1r[n],b1r[n],b1r[n],b1r[n]};  \
    _Pragma("unroll")                                                          \
    for (int kk = 0; kk < 4; ++kk) {                                           \
      bf16x8 ha = *(const bf16x8*)(h0p + kk*1024);                             \
      _Pragma("unroll")                                                        \
      for (int n = 0; n < 4; ++n)                                              \
        acc1[n] = __builtin_amdgcn_mfma_f32_16x16x32_bf16(ha, wih1[n][kk], acc1[n], 0, 0, 0); \
      SB();                                                                    \
    }                                                                          \
    _Pragma("unroll")                                                          \
    for (int kk = 0; kk < 4; ++kk) {                                           \
      bf16x8 ha = *(const bf16x8*)(h1p + kk*1024);                             \
      _Pragma("unroll")                                                        \
      for (int n = 0; n < 4; ++n) {                                            \
        bf16x8 wf = *(const bf16x8*)(wp + (n*4 + kk)*1024);                    \
        acc1[n] = __builtin_amdgcn_mfma_f32_16x16x32_bf16(ha, wf, acc1[n], 0, 0, 0); \
      }                                                                        \
      SB();                                                                    \
    }                                                                          \
    if (t > 0) {                                                               \
      char* hw = (char*)sH1f[cur ^ 1] + hwb;                                   \
      _Pragma("unroll")                                                        \
      for (int r = 0; r < 4; ++r) {                                            \
        float iv = sigm(acc1[0][r]);                                           \
        float fv = sigm(acc1[1][r]);                                           \
        float gv = tanh_fast(acc1[2][r]);                                      \
        float ov = sigm(acc1[3][r]);                                           \
        float c  = fv * c1r[r] + iv * gv;                                      \
        c1r[r] = c;                                                            \
        *(unsigned short*)(hw + r*16) = f2bf(ov * tanh_fast(c));               \
      }                                                                        \
    }                                                                          \
    SB();                                                                      \
  } while (0)

__global__ __launch_bounds__(512) __attribute__((amdgpu_waves_per_eu(2, 2)))
void fraud_lstm_kernel(
    const float* __restrict__ x,     const float* __restrict__ Wproj,
    const float* __restrict__ bproj, const float* __restrict__ Wih0,
    const float* __restrict__ Whh0,  const float* __restrict__ bih0,
    const float* __restrict__ bhh0,  const float* __restrict__ Wih1,
    const float* __restrict__ Whh1,  const float* __restrict__ bih1,
    const float* __restrict__ bhh1,  const float* __restrict__ Wh1,
    const float* __restrict__ bh1,   const float* __restrict__ Wh2,
    const float* __restrict__ bh2,   float* __restrict__ out)
{
  // LDS: 131072 + 8192 + 8192 + 12288 = 159744 B
  __shared__ unsigned short sWf[65536];     // Whh1 frags [wid][n*4+kk][lane][8]; also Wproj stage
  __shared__ unsigned short sH0f[2][2048];  // h0 dbuf, frag-linear [kk][lane][8]
  __shared__ unsigned short sH1f[2][2048];  // h1 dbuf
  __shared__ float sXB[3*1024];             // x triple buffer, frag-linear [kk][half][lane][4]

  const int tid  = threadIdx.x;
  const int lane = tid & 63;
  const int wid  = tid >> 6;
  const int lr   = lane & 15;
  const int lg   = lane >> 4;
  const int b0   = blockIdx.x * 16;
  const int g0   = wid*16 + lr;

  // ---------------- stage Wproj (f32 [64][64]) into sWf ----------------
  {
    float* sWp = reinterpret_cast<float*>(sWf);
    for (int i = tid; i < 4096; i += 512) sWp[i] = Wproj[i];
  }
  BAR();

  // ---------------- fold W0 = Wih0 @ Wproj (per-lane f32); fold biases ----------------
  float w0a[2][4][8];
  #pragma unroll
  for (int kk = 0; kk < 2; ++kk)
    #pragma unroll
    for (int n = 0; n < 4; ++n)
      #pragma unroll
      for (int j = 0; j < 8; ++j) w0a[kk][n][j] = 0.f;
  float bacc[4] = {0.f, 0.f, 0.f, 0.f};
  {
    const float* sWp = reinterpret_cast<const float*>(sWf);
    #pragma unroll 2
    for (int p = 0; p < 64; ++p) {
      float av[4];
      #pragma unroll
      for (int n = 0; n < 4; ++n) av[n] = Wih0[(n*128 + g0)*64 + p];
      float bp = bproj[p];
      #pragma unroll
      for (int n = 0; n < 4; ++n) bacc[n] += av[n] * bp;
      #pragma unroll
      for (int kk = 0; kk < 2; ++kk) {
        f32x4 wa = *(const f32x4*)&sWp[p*64 + kk*32 + lg*8];
        f32x4 wb = *(const f32x4*)&sWp[p*64 + kk*32 + lg*8 + 4];
        #pragma unroll
        for (int n = 0; n < 4; ++n)
          #pragma unroll
          for (int j = 0; j < 4; ++j) {
            w0a[kk][n][j]     += av[n] * wa[j];
            w0a[kk][n][4 + j] += av[n] * wb[j];
          }
      }
    }
  }
  bf16x8 w0f[2][4];
  #pragma unroll
  for (int kk = 0; kk < 2; ++kk)
    #pragma unroll
    for (int n = 0; n < 4; ++n)
      #pragma unroll
      for (int j = 0; j < 8; ++j) w0f[kk][n][j] = (__bf16)w0a[kk][n][j];

  float b0r[4], b1r[4];
  #pragma unroll
  for (int n = 0; n < 4; ++n) {
    const int g = n*128 + g0;
    b0r[n] = bih0[g] + bhh0[g] + bacc[n];
    b1r[n] = bih1[g] + bhh1[g];
  }
  BAR();   // Wproj stage dead; sWf free

  // ---------------- whh0, wih1 -> regs; Whh1 -> LDS frag-linear ----------------
  bf16x8 whh0[4][4], wih1[4][4];
  #pragma unroll
  for (int n = 0; n < 4; ++n)
    #pragma unroll
    for (int kk = 0; kk < 4; ++kk) {
      const int ro = (n*128 + g0)*128 + kk*32 + lg*8;
      const float* p0 = Whh0 + ro;
      const float* p1 = Wih1 + ro;
      #pragma unroll
      for (int j = 0; j < 8; ++j) {
        whh0[n][kk][j] = (__bf16)p0[j];
        wih1[n][kk][j] = (__bf16)p1[j];
      }
    }
  #pragma unroll
  for (int n = 0; n < 4; ++n)
    #pragma unroll
    for (int kk = 0; kk < 4; ++kk) {
      const int ro = (n*128 + g0)*128 + kk*32 + lg*8;
      const float* p2 = Whh1 + ro;
      bf16x8 w;
      #pragma unroll
      for (int j = 0; j < 8; ++j) w[j] = (__bf16)p2[j];
      *(bf16x8*)&sWf[((wid*16 + n*4 + kk)*64 + lane)*8] = w;
    }

  for (int i = tid; i < 2048; i += 512) {
    sH0f[0][i] = 0; sH0f[1][i] = 0; sH1f[0][i] = 0; sH1f[1][i] = 0;
  }

  // ---------------- x staging: frag-linear, per-lane permuted global source ----------------
  const float* xw = x + (size_t)(b0 + (lane & 15)) * (512*64)
                      + ((wid >> 1) & 1) * 32 + (lane >> 4) * 8 + (wid & 1) * 4;
  if (wid < 4) {
    async16(xw,      &sXB[0*1024 + wid*256]);   // x(0) -> buf0
    async16(xw + 64, &sXB[1*1024 + wid*256]);   // x(1) -> buf1
    asm volatile("s_waitcnt vmcnt(1)" ::: "memory");
  }
  BAR();

  const int hwb = (g0 >> 5)*1024 + ((g0 >> 3) & 3)*256 + (g0 & 7)*2 + lg*64;
  const int lb  = lane * 16;

  f32x4 c0r = {0.f,0.f,0.f,0.f}, c1r = {0.f,0.f,0.f,0.f};
  int bufR = 0, bufW = 2;

  // ================ main loop: region t = A(t) + B(t-1), one barrier ================
  #pragma unroll 1
  for (int t = 0; t < 512; ++t) {
    const int cur = t & 1;

    if (wid < 4 && t < 510) async16(xw + (t + 2)*64, &sXB[bufW*1024 + wid*256]);

    const char* xp  = (const char*)sXB + bufR*4096 + lb;
    const char* h0p = (const char*)sH0f[cur ^ 1] + lb;
    const char* h1p = (const char*)sH1f[cur] + lb;
    const char* wp  = (const char*)sWf + wid*16384 + lb;
    char* hw0 = (char*)sH0f[cur] + hwb;

    if (wid < 4) { SEC_A(); SEC_B(); }
    else         { SEC_B(); SEC_A(); }

    if (wid < 4) {
      if (t < 510) asm volatile("s_waitcnt vmcnt(1)" ::: "memory");
      else         asm volatile("s_waitcnt vmcnt(0)" ::: "memory");
    }
    BAR();   // h0(t), h1(t-1), x(t+1) visible

    bufR = (bufR == 2) ? 0 : bufR + 1;
    bufW = (bufW == 2) ? 0 : bufW + 1;
  }

  // ================ epilogue: B(511) ================
  {
    f32x4 acc1[4];
    #pragma unroll
    for (int n = 0; n < 4; ++n) acc1[n] = f32x4{b1r[n], b1r[n], b1r[n], b1r[n]};
    const char* h0p = (const char*)sH0f[1] + lb;   // h0(511)
    #pragma unroll
    for (int kk = 0; kk < 4; ++kk) {
      bf16x8 ha = *(const bf16x8*)(h0p + kk*1024);
      #pragma unroll
      for (int n = 0; n < 4; ++n)
        acc1[n] = __builtin_amdgcn_mfma_f32_16x16x32_bf16(ha, wih1[n][kk], acc1[n], 0, 0, 0);
    }
    const char* h1p = (const char*)sH1f[0] + lb;   // h1(510)
    const char* wp  = (const char*)sWf + wid*16384 + lb;
    #pragma unroll
    for (int kk = 0; kk < 4; ++kk) {
      bf16x8 ha = *(const bf16x8*)(h1p + kk*1024);
      #pragma unroll
      for (int n = 0; n < 4; ++n) {
        bf16x8 wf = *(const bf16x8*)(wp + (n*4 + kk)*1024);
        acc1[n] = __builtin_amdgcn_mfma_f32_16x16x32_bf16(ha, wf, acc1[n], 0, 0, 0);
      }
    }
    char* hw = (char*)sH1f[1] + hwb;               // h1(511)
    #pragma unroll
    for (int r = 0; r < 4; ++r) {
      float iv = sigm(acc1[0][r]);
      float fv = sigm(acc1[1][r]);
      float gv = tanh_fast(acc1[2][r]);
      float ov = sigm(acc1[3][r]);
      float c  = fv * c1r[r] + iv * gv;
      c1r[r] = c;
      *(unsigned short*)(hw + r*16) = f2bf(ov * tanh_fast(c));
    }
    BAR();
  }

  // ---------------- head: hid = relu(h1@Wh1^T + bh1); out = hid@Wh2^T + bh2 ----------------
  {
    int row = tid >> 5;
    int j0  = (tid & 31) * 2;
    float a0 = bh1[j0], a1 = bh1[j0 + 1];
    const float* w0 = Wh1 + j0*128;
    const float* w1 = w0 + 128;
    #pragma unroll 8
    for (int k = 0; k < 128; ++k) {
      float hv = bf2f(sH1f[1][(k >> 5)*512 + ((k >> 3) & 3)*128 + row*8 + (k & 7)]);
      a0 += hv * w0[k];
      a1 += hv * w1[k];
    }
    sXB[row*64 + j0]     = fmaxf(a0, 0.f);
    sXB[row*64 + j0 + 1] = fmaxf(a1, 0.f);
  }
  BAR();
  if (tid < 16) {
    float a = bh2[0];
    #pragma unroll 8
    for (int j = 0; j < 64; ++j) a += sXB[tid*64 + j] * Wh2[j];
    out[b0 + tid] = a;
  }
}

extern "C" void kernel_launch(void* const* d_in, const int* in_sizes, int n_in,
                              void* d_out, int out_size, void* d_ws, size_t ws_size,
                              hipStream_t stream) {
  (void)in_sizes; (void)n_in; (void)d_ws; (void)ws_size; (void)out_size;
  const float* x     = (const float*)d_in[0];
  const float* Wproj = (const float*)d_in[2];
  const float* bproj = (const float*)d_in[3];
  const float* Wih0  = (const float*)d_in[4];
  const float* Whh0  = (const float*)d_in[5];
  const float* bih0  = (const float*)d_in[6];
  const float* bhh0  = (const float*)d_in[7];
  const float* Wih1  = (const float*)d_in[8];
  const float* Whh1  = (const float*)d_in[9];
  const float* bih1  = (const float*)d_in[10];
  const float* bhh1  = (const float*)d_in[11];
  const float* Wh1   = (const float*)d_in[12];
  const float* bh1   = (const float*)d_in[13];
  const float* Wh2   = (const float*)d_in[14];
  const float* bh2   = (const float*)d_in[15];
  float* out = (float*)d_out;

  hipLaunchKernelGGL(fraud_lstm_kernel, dim3(64), dim3(512), 0, stream,
                     x, Wproj, bproj, Wih0, Whh0, bih0, bhh0,
                     Wih1, Whh1, bih1, bhh1, Wh1, bh1, Wh2, bh2, out);
}